// Round 2
// baseline (418.013 us; speedup 1.0000x reference)
//
#include <hip/hip_runtime.h>
#include <cstdint>
#include <cstddef>

typedef __attribute__((ext_vector_type(8))) short bf16x8;
typedef __attribute__((ext_vector_type(4))) float f32x4;
typedef __attribute__((ext_vector_type(4))) unsigned short ushort4_;

#define MFMA16(a, b, c) __builtin_amdgcn_mfma_f32_16x16x32_bf16((a), (b), (c), 0, 0, 0)

__device__ __forceinline__ unsigned short f2bf(float f) {
  union { float f; unsigned u; } c; c.f = f;
  unsigned r = c.u + 0x7fffu + ((c.u >> 16) & 1u);
  return (unsigned short)(r >> 16);
}

// async global->LDS, 16B per lane. LDS ptr must be wave-uniform; HW writes
// lane i at lds + i*16 (m97/m104). Swizzle goes into the SOURCE address.
__device__ __forceinline__ void gl_lds16(const unsigned short* g, unsigned short* l) {
  __builtin_amdgcn_global_load_lds(
      (const __attribute__((address_space(1))) void*)g,
      (__attribute__((address_space(3))) void*)l, 16, 0, 0);
}

// ---------------- fused prep: x->bf16 cvt + both weight transposes ----------------
__global__ __launch_bounds__(256) void k_prep(const float* __restrict__ x,
                                              unsigned short* __restrict__ xb,
                                              const float* __restrict__ wqkv,
                                              unsigned short* __restrict__ wqkvT,
                                              const float* __restrict__ wo,
                                              unsigned short* __restrict__ woT) {
  __shared__ unsigned short t[64][65];
  const int blk = blockIdx.x;
  const int tid = threadIdx.x;
  if (blk < 8192) {
    int i = blk * 256 + tid;
    float4 v = reinterpret_cast<const float4*>(x)[i];
    ushort4_ o;
    o.x = f2bf(v.x); o.y = f2bf(v.y); o.z = f2bf(v.z); o.w = f2bf(v.w);
    reinterpret_cast<ushort4_*>(xb)[i] = o;
    return;
  }
  const float* W;
  unsigned short* WT;
  int n0, k0, N;
  if (blk < 11264) {
    int local = blk - 8192;
    W = wqkv; WT = wqkvT; N = 6144;
    n0 = (local % 96) * 64; k0 = (local / 96) * 64;
  } else {
    int local = blk - 11264;
    W = wo; WT = woT; N = 2048;
    n0 = (local % 32) * 64; k0 = (local / 32) * 64;
  }
#pragma unroll
  for (int i = 0; i < 16; i++) {
    int li = tid + i * 256;
    int kk = li >> 6, nn = li & 63;
    t[kk][nn] = f2bf(W[(size_t)(k0 + kk) * N + (n0 + nn)]);
  }
  __syncthreads();
#pragma unroll
  for (int i = 0; i < 16; i++) {
    int li = tid + i * 256;
    int nn = li >> 6, kk = li & 63;
    WT[(size_t)(n0 + nn) * 2048 + (k0 + kk)] = t[kk][nn];
  }
}

// ---------------- old 128x128 2-phase GEMM (kept for out-projection) ----------------
template <int MODE>
__global__ __launch_bounds__(256) void k_gemm(const unsigned short* __restrict__ A,
                                              const unsigned short* __restrict__ Bt,
                                              const float* __restrict__ bias,
                                              unsigned short* __restrict__ qb,
                                              unsigned short* __restrict__ kb,
                                              unsigned short* __restrict__ vtb,
                                              float* __restrict__ outp) {
  __shared__ __align__(16) unsigned short As[128 * 64];
  __shared__ __align__(16) unsigned short Bs[128 * 64];
  const int tid = threadIdx.x;
  const int lane = tid & 63, wid = tid >> 6;
  const int quad = lane >> 4, l16 = lane & 15;
  const int wm = wid >> 1, wn = wid & 1;
  const int m0 = blockIdx.y * 128, n0 = blockIdx.x * 128;

  f32x4 acc[4][4];
#pragma unroll
  for (int i = 0; i < 4; i++)
#pragma unroll
    for (int j = 0; j < 4; j++) {
      f32x4 z = {0.f, 0.f, 0.f, 0.f};
      acc[i][j] = z;
    }

  for (int k0 = 0; k0 < 2048; k0 += 64) {
    __syncthreads();
#pragma unroll
    for (int i = 0; i < 4; i++) {
      int slotbase = wid * 64 + i * 256;
      int slot = slotbase + lane;
      int row = slot >> 3, chs = slot & 7, gch = chs ^ (row & 7);
      gl_lds16(A + (size_t)(m0 + row) * 2048 + k0 + gch * 8, &As[slotbase * 8]);
      gl_lds16(Bt + (size_t)(n0 + row) * 2048 + k0 + gch * 8, &Bs[slotbase * 8]);
    }
    __syncthreads();
#pragma unroll
    for (int kc = 0; kc < 2; kc++) {
      bf16x8 af[4], bfr[4];
#pragma unroll
      for (int mt = 0; mt < 4; mt++) {
        int r = wm * 64 + mt * 16 + l16;
        int ch = kc * 4 + quad;
        af[mt] = *reinterpret_cast<const bf16x8*>(&As[r * 64 + ((ch ^ (r & 7)) * 8)]);
      }
#pragma unroll
      for (int nt = 0; nt < 4; nt++) {
        int r = wn * 64 + nt * 16 + l16;
        int ch = kc * 4 + quad;
        bfr[nt] = *reinterpret_cast<const bf16x8*>(&Bs[r * 64 + ((ch ^ (r & 7)) * 8)]);
      }
#pragma unroll
      for (int mt = 0; mt < 4; mt++)
#pragma unroll
        for (int nt = 0; nt < 4; nt++)
          acc[mt][nt] = MFMA16(af[mt], bfr[nt], acc[mt][nt]);
    }
  }

  const int mbase = m0 + wm * 64;
  const int nbase = n0 + wn * 64;
  if (MODE == 0) {
#pragma unroll
    for (int nt = 0; nt < 4; nt++) {
      int n = nbase + nt * 16 + l16;
      float bv = bias[n];
      int seg = n >> 11;
      int h = (n >> 7) & 15;
      int d = n & 127;
#pragma unroll
      for (int mt = 0; mt < 4; mt++) {
        int mrow = mbase + mt * 16 + quad * 4;
        int b = mrow >> 11, s = mrow & 2047;
        if (seg == 2) {
          ushort4_ pk;
          pk.x = f2bf(acc[mt][nt][0] + bv);
          pk.y = f2bf(acc[mt][nt][1] + bv);
          pk.z = f2bf(acc[mt][nt][2] + bv);
          pk.w = f2bf(acc[mt][nt][3] + bv);
          *reinterpret_cast<ushort4_*>(vtb + ((size_t)(b * 16 + h) * 128 + d) * 2048 + s) = pk;
        } else {
          unsigned short* dst = (seg == 0 ? qb : kb);
          size_t base = (size_t)(b * 16 + h) * 2048;
#pragma unroll
          for (int rg = 0; rg < 4; rg++)
            dst[(base + (s + rg)) * 128 + d] = f2bf(acc[mt][nt][rg] + bv);
        }
      }
    }
  } else {
#pragma unroll
    for (int nt = 0; nt < 4; nt++) {
      int n = nbase + nt * 16 + l16;
#pragma unroll
      for (int mt = 0; mt < 4; mt++) {
        int mrow = mbase + mt * 16 + quad * 4;
#pragma unroll
        for (int rg = 0; rg < 4; rg++)
          outp[(size_t)(mrow + rg) * 2048 + n] = acc[mt][nt][rg];
      }
    }
  }
}

// ---------------- 256x256 8-phase counted-vmcnt GEMM (QKV) ----------------
// 512 thr = 8 waves (2M x 4N); per-wave C = 128x64 (8x4 frags). BK=64.
// LDS 128KB: As/Bs[2][256][64] bf16, chunk-XOR swizzle (0-conflict, proven).
// Phase (mh,nh) = one C-quadrant: 16 MFMA, A(mh) read ph0/ph2 (8 ds_read),
// B(nh) read ph0/ph1 (4 ds_read each) and kept in regs for ph2/ph3.
// Slot free: B(t) after ph1, A(t) after ph2. Stage map (2 gl_lds/phase):
//   ph0: A_lo(t+1)->buf^1   ph1: A_hi(t+1)->buf^1
//   ph2: B_lo(t+2)->buf     ph3: B_hi(t+2)->buf
// Safety: stage of slot X issues >=1 barrier after X's last ds_read completed
// (lgkmcnt(0) precedes the post-MFMA barrier). One s_waitcnt vmcnt(4) per
// K-tile (end ph3): keeps newest 2 half-tiles in flight; per-wave count +
// barrier => collective landing guarantee.
template <int MH>
__device__ __forceinline__ void lda_frag(const unsigned short* Asb, int wm, int quad,
                                         int l16, bf16x8 (&a)[4][2]) {
#pragma unroll
  for (int mi = 0; mi < 4; mi++)
#pragma unroll
    for (int kcc = 0; kcc < 2; kcc++) {
      int r = wm * 128 + MH * 64 + mi * 16 + l16;
      int ch = kcc * 4 + quad;
      a[mi][kcc] = *reinterpret_cast<const bf16x8*>(&Asb[r * 64 + ((ch ^ (r & 7)) * 8)]);
    }
}

template <int NH>
__device__ __forceinline__ void ldb_frag(const unsigned short* Bsb, int wn, int quad,
                                         int l16, bf16x8 (&b)[2][2][2]) {
#pragma unroll
  for (int ni = 0; ni < 2; ni++)
#pragma unroll
    for (int kcc = 0; kcc < 2; kcc++) {
      int r = wn * 64 + NH * 32 + ni * 16 + l16;
      int ch = kcc * 4 + quad;
      b[NH][ni][kcc] = *reinterpret_cast<const bf16x8*>(&Bsb[r * 64 + ((ch ^ (r & 7)) * 8)]);
    }
}

template <int MH, int NH>
__device__ __forceinline__ void phase_mfma(f32x4 (&acc)[8][4], const bf16x8 (&a)[4][2],
                                           const bf16x8 (&b)[2][2][2]) {
  __builtin_amdgcn_s_setprio(1);
#pragma unroll
  for (int kcc = 0; kcc < 2; kcc++)
#pragma unroll
    for (int mi = 0; mi < 4; mi++)
#pragma unroll
      for (int ni = 0; ni < 2; ni++)
        acc[MH * 4 + mi][NH * 2 + ni] =
            MFMA16(a[mi][kcc], b[NH][ni][kcc], acc[MH * 4 + mi][NH * 2 + ni]);
  __builtin_amdgcn_s_setprio(0);
}

#define G2_BAR asm volatile("s_barrier" ::: "memory")
#define G2_LGKM0                                      \
  asm volatile("s_waitcnt lgkmcnt(0)" ::: "memory"); \
  __builtin_amdgcn_sched_barrier(0)
#define G2_VM4 asm volatile("s_waitcnt vmcnt(4)" ::: "memory")

__global__ __launch_bounds__(512, 2) void k_gemm2(const unsigned short* __restrict__ A,
                                                  const unsigned short* __restrict__ Bt,
                                                  const float* __restrict__ bias,
                                                  unsigned short* __restrict__ qb,
                                                  unsigned short* __restrict__ kb,
                                                  unsigned short* __restrict__ vtb,
                                                  int ntn) {
  __shared__ __align__(16) unsigned short As[2][256 * 64];
  __shared__ __align__(16) unsigned short Bs[2][256 * 64];
  const int tid = threadIdx.x;
  const int lane = tid & 63, wid = tid >> 6;
  const int quad = lane >> 4, l16 = lane & 15;
  const int wm = wid >> 2, wn = wid & 3;

  // XCD-aware swizzle (grid % 8 == 0): chunk per XCD for L2 panel reuse
  const int nwg = gridDim.x, bid = blockIdx.x;
  const int cpx = nwg >> 3;
  const int swz = (bid & 7) * cpx + (bid >> 3);
  const int tm = swz / ntn, tn = swz % ntn;
  const int m0 = tm * 256, n0 = tn * 256;

  f32x4 acc[8][4];
#pragma unroll
  for (int i = 0; i < 8; i++)
#pragma unroll
    for (int j = 0; j < 4; j++) {
      f32x4 z = {0.f, 0.f, 0.f, 0.f};
      acc[i][j] = z;
    }

  // stage one 128-row half-tile (16KB) = 2 gl_lds per thread
  auto stA = [&](int tsrc, int buf, int rbase) {
#pragma unroll
    for (int s = 0; s < 2; s++) {
      int slotbase = s * 512 + wid * 64;
      int slot = slotbase + lane;
      int row = rbase + (slot >> 3);
      int ch = (slot & 7) ^ (row & 7);
      gl_lds16(A + (size_t)(m0 + row) * 2048 + tsrc * 64 + ch * 8,
               &As[buf][rbase * 64 + slotbase * 8]);
    }
  };
  auto stB = [&](int tsrc, int buf, int rbase) {
#pragma unroll
    for (int s = 0; s < 2; s++) {
      int slotbase = s * 512 + wid * 64;
      int slot = slotbase + lane;
      int row = rbase + (slot >> 3);
      int ch = (slot & 7) ^ (row & 7);
      gl_lds16(Bt + (size_t)(n0 + row) * 2048 + tsrc * 64 + ch * 8,
               &Bs[buf][rbase * 64 + slotbase * 8]);
    }
  };

  bf16x8 a[4][2];
  bf16x8 b[2][2][2];

  // prologue: tile0 (A+B) + tile1 B  -> 12 loads; need tile0 (first 8) landed
  stA(0, 0, 0); stA(0, 0, 128);
  stB(0, 0, 0); stB(0, 0, 128);
  stB(1, 1, 0); stB(1, 1, 128);
  G2_VM4;
  G2_BAR;

  const int nt = 32;  // K=2048 / BK=64
  for (int t = 0; t < nt; t++) {
    const int buf = t & 1;
    const unsigned short* Asb = &As[buf][0];
    const unsigned short* Bsb = &Bs[buf][0];
    const int tA = (t + 1 < nt) ? t + 1 : t;  // dummy clamp keeps vmcnt uniform
    const int tB = (t + 2 < nt) ? t + 2 : t;

    // ---- phase 0: quadrant (m0,n0) ----
    lda_frag<0>(Asb, wm, quad, l16, a);
    ldb_frag<0>(Bsb, wn, quad, l16, b);
    stA(tA, buf ^ 1, 0);
    G2_BAR;
    G2_LGKM0;
    phase_mfma<0, 0>(acc, a, b);
    G2_BAR;

    // ---- phase 1: quadrant (m0,n1) ----
    ldb_frag<1>(Bsb, wn, quad, l16, b);
    stA(tA, buf ^ 1, 128);
    G2_BAR;
    G2_LGKM0;
    phase_mfma<0, 1>(acc, a, b);
    G2_BAR;

    // ---- phase 2: quadrant (m1,n0) ---- (B(t) slots free after ph1)
    lda_frag<1>(Asb, wm, quad, l16, a);
    stB(tB, buf, 0);
    G2_BAR;
    G2_LGKM0;
    phase_mfma<1, 0>(acc, a, b);
    G2_BAR;

    // ---- phase 3: quadrant (m1,n1) ----
    stB(tB, buf, 128);
    G2_BAR;
    phase_mfma<1, 1>(acc, a, b);
    G2_VM4;  // next tile's A+B landed (counted: keep newest 2 half-tiles)
    G2_BAR;
  }
  asm volatile("s_waitcnt vmcnt(0)" ::: "memory");  // drain dummy prefetches

  // epilogue: QKV scatter (same mapping as old MODE 0, 8 m-frags)
  const int mbase = m0 + wm * 128;
  const int nbase = n0 + wn * 64;
#pragma unroll
  for (int ntf = 0; ntf < 4; ntf++) {
    int n = nbase + ntf * 16 + l16;
    float bv = bias[n];
    int seg = n >> 11;  // 0=q,1=k,2=v  (tiles never straddle: 2048%256==0)
    int h = (n >> 7) & 15;
    int d = n & 127;
#pragma unroll
    for (int mt = 0; mt < 8; mt++) {
      int mrow = mbase + mt * 16 + quad * 4;
      int bb = mrow >> 11, s = mrow & 2047;
      if (seg == 2) {
        ushort4_ pk;
        pk.x = f2bf(acc[mt][ntf][0] + bv);
        pk.y = f2bf(acc[mt][ntf][1] + bv);
        pk.z = f2bf(acc[mt][ntf][2] + bv);
        pk.w = f2bf(acc[mt][ntf][3] + bv);
        *reinterpret_cast<ushort4_*>(vtb + ((size_t)(bb * 16 + h) * 128 + d) * 2048 + s) = pk;
      } else {
        unsigned short* dst = (seg == 0 ? qb : kb);
        size_t base = (size_t)(bb * 16 + h) * 2048;
#pragma unroll
        for (int rg = 0; rg < 4; rg++)
          dst[(base + (s + rg)) * 128 + d] = f2bf(acc[mt][ntf][rg] + bv);
      }
    }
  }
}

// ---------------- flash attention (unchanged from R1) ----------------
__global__ __launch_bounds__(256, 2) void k_attn(const unsigned short* __restrict__ qb,
                                                 const unsigned short* __restrict__ kb,
                                                 const unsigned short* __restrict__ vtb,
                                                 unsigned short* __restrict__ ctx) {
  __shared__ __align__(16) unsigned short Ks[2][64 * 128];
  __shared__ __align__(16) unsigned short Vs[2][128 * 64];
  __shared__ __align__(16) unsigned short Ps[128 * 64];
  const int bx = blockIdx.x;
  const int g = (bx & 1) ? (15 - (bx >> 1)) : (bx >> 1);
  const int qt = (blockIdx.y < 16) ? g : (15 - g);
  const int bh = blockIdx.y;
  const int tid = threadIdx.x;
  const int lane = tid & 63, w = tid >> 6;
  const int quad = lane >> 4, l16 = lane & 15;
  const int qbase = qt * 128;
  const unsigned short* Qh = qb + (size_t)bh * 2048 * 128;
  const unsigned short* Kh = kb + (size_t)bh * 2048 * 128;
  const unsigned short* Vh = vtb + (size_t)bh * 128 * 2048;

  const int q_lo = qbase + w * 32;
  const int nkv = 2 * qt + 2;
  const float sl2 = 0.12751741f;

  bf16x8 qf[2][4];
#pragma unroll
  for (int half = 0; half < 2; half++)
#pragma unroll
    for (int kc = 0; kc < 4; kc++)
      qf[half][kc] = *reinterpret_cast<const bf16x8*>(
          Qh + (size_t)(q_lo + half * 16 + l16) * 128 + kc * 32 + quad * 8);

  f32x4 o[2][8];
#pragma unroll
  for (int half = 0; half < 2; half++)
#pragma unroll
    for (int dt = 0; dt < 8; dt++) {
      f32x4 z = {0.f, 0.f, 0.f, 0.f};
      o[half][dt] = z;
    }
  float m_run[2] = {-1e30f, -1e30f}, l_run[2] = {0.f, 0.f};

  auto stage = [&](int kvb, int bsel) {
    unsigned short* Kd = &Ks[bsel][0];
    unsigned short* Vd = &Vs[bsel][0];
#pragma unroll
    for (int i = 0; i < 4; i++) {
      int slotbase = i * 256 + w * 64;
      int slot = slotbase + lane;
      int rowk = slot >> 4, chk = (slot & 15) ^ (rowk & 7);
      gl_lds16(Kh + (size_t)(kvb + rowk) * 128 + chk * 8, Kd + slotbase * 8);
      int rowv = slot >> 3, chv = (slot & 7) ^ (rowv & 7);
      gl_lds16(Vh + (size_t)rowv * 2048 + kvb + chv * 8, Vd + slotbase * 8);
    }
  };

  stage(0, 0);

  for (int kv = 0; kv < nkv; kv++) {
    const int kvb = kv * 64;
    const int cur = kv & 1;
    asm volatile("s_waitcnt vmcnt(0)" ::: "memory");
    asm volatile("s_barrier" ::: "memory");
    if (kv + 1 < nkv) stage(kvb + 64, cur ^ 1);
    if (kvb > q_lo + 31) continue;

    const unsigned short* Kc = &Ks[cur][0];
    const unsigned short* Vc = &Vs[cur][0];

    f32x4 sacc[2][4];
#pragma unroll
    for (int half = 0; half < 2; half++)
#pragma unroll
      for (int nt = 0; nt < 4; nt++) {
        f32x4 z = {0.f, 0.f, 0.f, 0.f};
        sacc[half][nt] = z;
      }
#pragma unroll
    for (int kc = 0; kc < 4; kc++) {
#pragma unroll
      for (int nt = 0; nt < 4; nt++) {
        int r = nt * 16 + l16, ch = kc * 4 + quad;
        bf16x8 kf = *reinterpret_cast<const bf16x8*>(&Kc[r * 128 + ((ch ^ (r & 7)) * 8)]);
        sacc[0][nt] = MFMA16(kf, qf[0][kc], sacc[0][nt]);
        sacc[1][nt] = MFMA16(kf, qf[1][kc], sacc[1][nt]);
      }
    }

    const bool needmask = (kvb + 63) > q_lo;
#pragma unroll
    for (int half = 0; half < 2; half++) {
      const int qabs = q_lo + half * 16 + l16;
      float tmax = -1e30f;
#pragma unroll
      for (int nt = 0; nt < 4; nt++)
#pragma unroll
        for (int rg = 0; rg < 4; rg++) {
          float v = sacc[half][nt][rg] * sl2;
          if (needmask && (kvb + nt * 16 + quad * 4 + rg) > qabs) v = -1e30f;
          sacc[half][nt][rg] = v;
          tmax = fmaxf(tmax, v);
        }
      tmax = fmaxf(tmax, __shfl_xor(tmax, 16));
      tmax = fmaxf(tmax, __shfl_xor(tmax, 32));
      float mnew = fmaxf(m_run[half], tmax);
      float alpha = exp2f(m_run[half] - mnew);
      m_run[half] = mnew;
      float rsum = 0.f;
#pragma unroll
      for (int nt = 0; nt < 4; nt++)
#pragma unroll
        for (int rg = 0; rg < 4; rg++) {
          float p = exp2f(sacc[half][nt][rg] - mnew);
          sacc[half][nt][rg] = p;
          rsum += p;
        }
      rsum += __shfl_xor(rsum, 16);
      rsum += __shfl_xor(rsum, 32);
      l_run[half] = l_run[half] * alpha + rsum;
#pragma unroll
      for (int dt = 0; dt < 8; dt++)
#pragma unroll
        for (int rg = 0; rg < 4; rg++) o[half][dt][rg] *= alpha;

#pragma unroll
      for (int nt = 0; nt < 4; nt++) {
        ushort4_ pk;
        pk.x = f2bf(sacc[half][nt][0]);
        pk.y = f2bf(sacc[half][nt][1]);
        pk.z = f2bf(sacc[half][nt][2]);
        pk.w = f2bf(sacc[half][nt][3]);
        int chunk = nt * 2 + (quad >> 1);
        *reinterpret_cast<ushort4_*>(
            &Ps[(w * 32 + half * 16 + l16) * 64 + ((chunk ^ (l16 & 7)) * 8) +
                (quad & 1) * 4]) = pk;
      }
    }
    asm volatile("s_waitcnt lgkmcnt(0)" ::: "memory");

#pragma unroll
    for (int kc = 0; kc < 2; kc++) {
      int chunkr = kc * 4 + quad;
      bf16x8 pf0 = *reinterpret_cast<const bf16x8*>(
          &Ps[(w * 32 + l16) * 64 + ((chunkr ^ (l16 & 7)) * 8)]);
      bf16x8 pf1 = *reinterpret_cast<const bf16x8*>(
          &Ps[(w * 32 + 16 + l16) * 64 + ((chunkr ^ (l16 & 7)) * 8)]);
#pragma unroll
      for (int dt = 0; dt < 8; dt++) {
        int r = dt * 16 + l16, ch = kc * 4 + quad;
        bf16x8 vf = *reinterpret_cast<const bf16x8*>(&Vc[r * 64 + ((ch ^ (r & 7)) * 8)]);
        o[0][dt] = MFMA16(vf, pf0, o[0][dt]);
        o[1][dt] = MFMA16(vf, pf1, o[1][dt]);
      }
    }
  }

  const int b = bh >> 4, h = bh & 15;
#pragma unroll
  for (int half = 0; half < 2; half++) {
    const float inv = 1.f / l_run[half];
    const int s = q_lo + half * 16 + l16;
#pragma unroll
    for (int dt = 0; dt < 8; dt++) {
      int d0 = dt * 16 + quad * 4;
      ushort4_ pk;
      pk.x = f2bf(o[half][dt][0] * inv);
      pk.y = f2bf(o[half][dt][1] * inv);
      pk.z = f2bf(o[half][dt][2] * inv);
      pk.w = f2bf(o[half][dt][3] * inv);
      *reinterpret_cast<ushort4_*>(
          &ctx[((size_t)b * 2048 + s) * 2048 + h * 128 + d0]) = pk;
    }
  }
}

extern "C" void kernel_launch(void* const* d_in, const int* in_sizes, int n_in,
                              void* d_out, int out_size, void* d_ws, size_t ws_size,
                              hipStream_t stream) {
  const float* x = (const float*)d_in[0];
  const float* w_qkv = (const float*)d_in[1];
  const float* b_qkv = (const float*)d_in[2];
  const float* w_o = (const float*)d_in[3];
  float* outp = (float*)d_out;

  unsigned short* ws = (unsigned short*)d_ws;
  unsigned short* xb    = ws;
  unsigned short* wqkvT = xb + 8388608;
  unsigned short* woT   = wqkvT + 12582912;
  unsigned short* qbuf  = woT + 4194304;
  unsigned short* kbuf  = qbuf + 8388608;
  unsigned short* vtbuf = kbuf + 8388608;
  unsigned short* ctxb  = vtbuf + 8388608;

  k_prep<<<12288, 256, 0, stream>>>(x, xb, w_qkv, wqkvT, w_o, woT);
  k_gemm2<<<384, 512, 0, stream>>>(xb, wqkvT, b_qkv, qbuf, kbuf, vtbuf, 24);
  k_attn<<<dim3(16, 32), 256, 0, stream>>>(qbuf, kbuf, vtbuf, ctxb);
  k_gemm<1><<<dim3(16, 32), 256, 0, stream>>>(ctxb, woT, nullptr, nullptr, nullptr, nullptr, outp);
}

// Round 3
// 405.869 us; speedup vs baseline: 1.0299x; 1.0299x over previous
//
#include <hip/hip_runtime.h>
#include <cstdint>
#include <cstddef>

typedef __attribute__((ext_vector_type(8))) short bf16x8;
typedef __attribute__((ext_vector_type(4))) float f32x4;
typedef __attribute__((ext_vector_type(4))) unsigned short ushort4_;

#define MFMA16(a, b, c) __builtin_amdgcn_mfma_f32_16x16x32_bf16((a), (b), (c), 0, 0, 0)

__device__ __forceinline__ unsigned short f2bf(float f) {
  union { float f; unsigned u; } c; c.f = f;
  unsigned r = c.u + 0x7fffu + ((c.u >> 16) & 1u);
  return (unsigned short)(r >> 16);
}

// async global->LDS, 16B per lane. LDS ptr must be wave-uniform; HW writes
// lane i at lds + i*16 (m97/m104). Swizzle goes into the SOURCE address.
__device__ __forceinline__ void gl_lds16(const unsigned short* g, unsigned short* l) {
  __builtin_amdgcn_global_load_lds(
      (const __attribute__((address_space(1))) void*)g,
      (__attribute__((address_space(3))) void*)l, 16, 0, 0);
}

// ---------------- fused prep: x->bf16 cvt + both weight transposes ----------------
// blocks [0,8192): cvt; [8192,11264): w_qkv^T (96x32); [11264,12288): w_o^T (32x32)
__global__ __launch_bounds__(256) void k_prep(const float* __restrict__ x,
                                              unsigned short* __restrict__ xb,
                                              const float* __restrict__ wqkv,
                                              unsigned short* __restrict__ wqkvT,
                                              const float* __restrict__ wo,
                                              unsigned short* __restrict__ woT) {
  __shared__ unsigned short t[64][65];
  const int blk = blockIdx.x;
  const int tid = threadIdx.x;
  if (blk < 8192) {
    int i = blk * 256 + tid;
    float4 v = reinterpret_cast<const float4*>(x)[i];
    ushort4_ o;
    o.x = f2bf(v.x); o.y = f2bf(v.y); o.z = f2bf(v.z); o.w = f2bf(v.w);
    reinterpret_cast<ushort4_*>(xb)[i] = o;
    return;
  }
  const float* W;
  unsigned short* WT;
  int n0, k0, N;
  if (blk < 11264) {
    int local = blk - 8192;
    W = wqkv; WT = wqkvT; N = 6144;
    n0 = (local % 96) * 64; k0 = (local / 96) * 64;
  } else {
    int local = blk - 11264;
    W = wo; WT = woT; N = 2048;
    n0 = (local % 32) * 64; k0 = (local / 32) * 64;
  }
#pragma unroll
  for (int i = 0; i < 16; i++) {
    int li = tid + i * 256;
    int kk = li >> 6, nn = li & 63;
    t[kk][nn] = f2bf(W[(size_t)(k0 + kk) * N + (n0 + nn)]);
  }
  __syncthreads();
#pragma unroll
  for (int i = 0; i < 16; i++) {
    int li = tid + i * 256;
    int nn = li >> 6, kk = li & 63;
    WT[(size_t)(n0 + nn) * 2048 + (k0 + kk)] = t[kk][nn];
  }
}

// ---------------- GEMM: C[128x128]/block, A[M][2048] bf16, Bt[N][2048] bf16
// MODE: 0=Q rows, 1=K rows, 2=V^T (transposed bf16), 3=out-proj fp32.
// Split QKV into per-segment launches (N=2048 each) so rocprof top-5 exposes
// the full per-kernel breakdown (QKV monolith hid everything else).
template <int MODE>
__global__ __launch_bounds__(256) void k_gemm(const unsigned short* __restrict__ A,
                                              const unsigned short* __restrict__ Bt,
                                              const float* __restrict__ bias,
                                              unsigned short* __restrict__ dst,
                                              float* __restrict__ outp) {
  __shared__ __align__(16) unsigned short As[128 * 64];
  __shared__ __align__(16) unsigned short Bs[128 * 64];
  const int tid = threadIdx.x;
  const int lane = tid & 63, wid = tid >> 6;
  const int quad = lane >> 4, l16 = lane & 15;
  const int wm = wid >> 1, wn = wid & 1;
  const int m0 = blockIdx.y * 128, n0 = blockIdx.x * 128;

  f32x4 acc[4][4];
#pragma unroll
  for (int i = 0; i < 4; i++)
#pragma unroll
    for (int j = 0; j < 4; j++) {
      f32x4 z = {0.f, 0.f, 0.f, 0.f};
      acc[i][j] = z;
    }

  for (int k0 = 0; k0 < 2048; k0 += 64) {
    __syncthreads();
#pragma unroll
    for (int i = 0; i < 4; i++) {
      int slotbase = wid * 64 + i * 256;
      int slot = slotbase + lane;
      int row = slot >> 3, chs = slot & 7, gch = chs ^ (row & 7);
      gl_lds16(A + (size_t)(m0 + row) * 2048 + k0 + gch * 8, &As[slotbase * 8]);
      gl_lds16(Bt + (size_t)(n0 + row) * 2048 + k0 + gch * 8, &Bs[slotbase * 8]);
    }
    __syncthreads();
#pragma unroll
    for (int kc = 0; kc < 2; kc++) {
      bf16x8 af[4], bfr[4];
#pragma unroll
      for (int mt = 0; mt < 4; mt++) {
        int r = wm * 64 + mt * 16 + l16;
        int ch = kc * 4 + quad;
        af[mt] = *reinterpret_cast<const bf16x8*>(&As[r * 64 + ((ch ^ (r & 7)) * 8)]);
      }
#pragma unroll
      for (int nt = 0; nt < 4; nt++) {
        int r = wn * 64 + nt * 16 + l16;
        int ch = kc * 4 + quad;
        bfr[nt] = *reinterpret_cast<const bf16x8*>(&Bs[r * 64 + ((ch ^ (r & 7)) * 8)]);
      }
#pragma unroll
      for (int mt = 0; mt < 4; mt++)
#pragma unroll
        for (int nt = 0; nt < 4; nt++)
          acc[mt][nt] = MFMA16(af[mt], bfr[nt], acc[mt][nt]);
    }
  }

  const int mbase = m0 + wm * 64;
  const int nbase = n0 + wn * 64;
  if (MODE == 3) {
#pragma unroll
    for (int nt = 0; nt < 4; nt++) {
      int n = nbase + nt * 16 + l16;
#pragma unroll
      for (int mt = 0; mt < 4; mt++) {
        int mrow = mbase + mt * 16 + quad * 4;
#pragma unroll
        for (int rg = 0; rg < 4; rg++)
          outp[(size_t)(mrow + rg) * 2048 + n] = acc[mt][nt][rg];
      }
    }
  } else {
#pragma unroll
    for (int nt = 0; nt < 4; nt++) {
      int n = nbase + nt * 16 + l16;  // within this 2048-wide segment
      float bv = bias[n];
      int h = n >> 7, d = n & 127;
#pragma unroll
      for (int mt = 0; mt < 4; mt++) {
        int mrow = mbase + mt * 16 + quad * 4;
        int b = mrow >> 11, s = mrow & 2047;
        if (MODE == 2) {
          ushort4_ pk;
          pk.x = f2bf(acc[mt][nt][0] + bv);
          pk.y = f2bf(acc[mt][nt][1] + bv);
          pk.z = f2bf(acc[mt][nt][2] + bv);
          pk.w = f2bf(acc[mt][nt][3] + bv);
          *reinterpret_cast<ushort4_*>(dst + ((size_t)(b * 16 + h) * 128 + d) * 2048 + s) = pk;
        } else {
          size_t base = (size_t)(b * 16 + h) * 2048;
#pragma unroll
          for (int rg = 0; rg < 4; rg++)
            dst[(base + (s + rg)) * 128 + d] = f2bf(acc[mt][nt][rg] + bv);
        }
      }
    }
  }
}

// ---------------- flash attention: 128 q-rows, 4 waves x 32 rows ----------------
// S^T = K·Q^T orientation, per-lane online softmax, O^T accumulation.
// KV tiles of 64, double-buffered, async prefetch across the barrier.
// LDS 80KB -> 2 blocks/CU. qt remap balances causal work across CUs (R1).
// R3: + defer-max (T13, skip O-rescale when tile max grows <= 8 in log2
// units; P bounded by 2^8, f32 accum headroom fine) and s_setprio around
// MFMA clusters (T5; attn blocks are independent -> scheduler has role
// diversity, the regime where m191 measured +4-7%).
__global__ __launch_bounds__(256, 2) void k_attn(const unsigned short* __restrict__ qb,
                                                 const unsigned short* __restrict__ kb,
                                                 const unsigned short* __restrict__ vtb,
                                                 unsigned short* __restrict__ ctx) {
  __shared__ __align__(16) unsigned short Ks[2][64 * 128];
  __shared__ __align__(16) unsigned short Vs[2][128 * 64];
  __shared__ __align__(16) unsigned short Ps[128 * 64];
  const int bx = blockIdx.x;
  const int g = (bx & 1) ? (15 - (bx >> 1)) : (bx >> 1);
  const int qt = (blockIdx.y < 16) ? g : (15 - g);
  const int bh = blockIdx.y;
  const int tid = threadIdx.x;
  const int lane = tid & 63, w = tid >> 6;
  const int quad = lane >> 4, l16 = lane & 15;
  const int qbase = qt * 128;
  const unsigned short* Qh = qb + (size_t)bh * 2048 * 128;
  const unsigned short* Kh = kb + (size_t)bh * 2048 * 128;
  const unsigned short* Vh = vtb + (size_t)bh * 128 * 2048;

  const int q_lo = qbase + w * 32;
  const int nkv = 2 * qt + 2;
  const float sl2 = 0.12751741f;  // (1/sqrt(128)) * log2(e)

  bf16x8 qf[2][4];
#pragma unroll
  for (int half = 0; half < 2; half++)
#pragma unroll
    for (int kc = 0; kc < 4; kc++)
      qf[half][kc] = *reinterpret_cast<const bf16x8*>(
          Qh + (size_t)(q_lo + half * 16 + l16) * 128 + kc * 32 + quad * 8);

  f32x4 o[2][8];
#pragma unroll
  for (int half = 0; half < 2; half++)
#pragma unroll
    for (int dt = 0; dt < 8; dt++) {
      f32x4 z = {0.f, 0.f, 0.f, 0.f};
      o[half][dt] = z;
    }
  float m_run[2] = {-1e30f, -1e30f}, l_run[2] = {0.f, 0.f};

  auto stage = [&](int kvb, int bsel) {
    unsigned short* Kd = &Ks[bsel][0];
    unsigned short* Vd = &Vs[bsel][0];
#pragma unroll
    for (int i = 0; i < 4; i++) {
      int slotbase = i * 256 + w * 64;
      int slot = slotbase + lane;
      int rowk = slot >> 4, chk = (slot & 15) ^ (rowk & 7);
      gl_lds16(Kh + (size_t)(kvb + rowk) * 128 + chk * 8, Kd + slotbase * 8);
      int rowv = slot >> 3, chv = (slot & 7) ^ (rowv & 7);
      gl_lds16(Vh + (size_t)rowv * 2048 + kvb + chv * 8, Vd + slotbase * 8);
    }
  };

  stage(0, 0);

  for (int kv = 0; kv < nkv; kv++) {
    const int kvb = kv * 64;
    const int cur = kv & 1;
    asm volatile("s_waitcnt vmcnt(0)" ::: "memory");
    asm volatile("s_barrier" ::: "memory");
    if (kv + 1 < nkv) stage(kvb + 64, cur ^ 1);
    if (kvb > q_lo + 31) continue;

    const unsigned short* Kc = &Ks[cur][0];
    const unsigned short* Vc = &Vs[cur][0];

    f32x4 sacc[2][4];
#pragma unroll
    for (int half = 0; half < 2; half++)
#pragma unroll
      for (int nt = 0; nt < 4; nt++) {
        f32x4 z = {0.f, 0.f, 0.f, 0.f};
        sacc[half][nt] = z;
      }
    __builtin_amdgcn_s_setprio(1);
#pragma unroll
    for (int kc = 0; kc < 4; kc++) {
#pragma unroll
      for (int nt = 0; nt < 4; nt++) {
        int r = nt * 16 + l16, ch = kc * 4 + quad;
        bf16x8 kf = *reinterpret_cast<const bf16x8*>(&Kc[r * 128 + ((ch ^ (r & 7)) * 8)]);
        sacc[0][nt] = MFMA16(kf, qf[0][kc], sacc[0][nt]);
        sacc[1][nt] = MFMA16(kf, qf[1][kc], sacc[1][nt]);
      }
    }
    __builtin_amdgcn_s_setprio(0);

    const bool needmask = (kvb + 63) > q_lo;
#pragma unroll
    for (int half = 0; half < 2; half++) {
      const int qabs = q_lo + half * 16 + l16;
      float tmax = -1e30f;
#pragma unroll
      for (int nt = 0; nt < 4; nt++)
#pragma unroll
        for (int rg = 0; rg < 4; rg++) {
          float v = sacc[half][nt][rg] * sl2;
          if (needmask && (kvb + nt * 16 + quad * 4 + rg) > qabs) v = -1e30f;
          sacc[half][nt][rg] = v;
          tmax = fmaxf(tmax, v);
        }
      tmax = fmaxf(tmax, __shfl_xor(tmax, 16));
      tmax = fmaxf(tmax, __shfl_xor(tmax, 32));
      // defer-max (T13): only rescale when the running max grew by >8 (log2
      // units). Deferred P is bounded by 2^8; f32 O/l accum has headroom.
      if (!__all(tmax - m_run[half] <= 8.f)) {
        float mnew = fmaxf(m_run[half], tmax);
        float alpha = exp2f(m_run[half] - mnew);
        m_run[half] = mnew;
        l_run[half] *= alpha;
#pragma unroll
        for (int dt = 0; dt < 8; dt++)
#pragma unroll
          for (int rg = 0; rg < 4; rg++) o[half][dt][rg] *= alpha;
      }
      const float mcur = m_run[half];
      float rsum = 0.f;
#pragma unroll
      for (int nt = 0; nt < 4; nt++)
#pragma unroll
        for (int rg = 0; rg < 4; rg++) {
          float p = exp2f(sacc[half][nt][rg] - mcur);
          sacc[half][nt][rg] = p;
          rsum += p;
        }
      rsum += __shfl_xor(rsum, 16);
      rsum += __shfl_xor(rsum, 32);
      l_run[half] += rsum;

#pragma unroll
      for (int nt = 0; nt < 4; nt++) {
        ushort4_ pk;
        pk.x = f2bf(sacc[half][nt][0]);
        pk.y = f2bf(sacc[half][nt][1]);
        pk.z = f2bf(sacc[half][nt][2]);
        pk.w = f2bf(sacc[half][nt][3]);
        int chunk = nt * 2 + (quad >> 1);
        *reinterpret_cast<ushort4_*>(
            &Ps[(w * 32 + half * 16 + l16) * 64 + ((chunk ^ (l16 & 7)) * 8) +
                (quad & 1) * 4]) = pk;
      }
    }
    asm volatile("s_waitcnt lgkmcnt(0)" ::: "memory");  // same-wave rows only

    __builtin_amdgcn_s_setprio(1);
#pragma unroll
    for (int kc = 0; kc < 2; kc++) {
      int chunkr = kc * 4 + quad;
      bf16x8 pf0 = *reinterpret_cast<const bf16x8*>(
          &Ps[(w * 32 + l16) * 64 + ((chunkr ^ (l16 & 7)) * 8)]);
      bf16x8 pf1 = *reinterpret_cast<const bf16x8*>(
          &Ps[(w * 32 + 16 + l16) * 64 + ((chunkr ^ (l16 & 7)) * 8)]);
#pragma unroll
      for (int dt = 0; dt < 8; dt++) {
        int r = dt * 16 + l16, ch = kc * 4 + quad;
        bf16x8 vf = *reinterpret_cast<const bf16x8*>(&Vc[r * 64 + ((ch ^ (r & 7)) * 8)]);
        o[0][dt] = MFMA16(vf, pf0, o[0][dt]);
        o[1][dt] = MFMA16(vf, pf1, o[1][dt]);
      }
    }
    __builtin_amdgcn_s_setprio(0);
  }

  const int b = bh >> 4, h = bh & 15;
#pragma unroll
  for (int half = 0; half < 2; half++) {
    const float inv = 1.f / l_run[half];
    const int s = q_lo + half * 16 + l16;
#pragma unroll
    for (int dt = 0; dt < 8; dt++) {
      int d0 = dt * 16 + quad * 4;
      ushort4_ pk;
      pk.x = f2bf(o[half][dt][0] * inv);
      pk.y = f2bf(o[half][dt][1] * inv);
      pk.z = f2bf(o[half][dt][2] * inv);
      pk.w = f2bf(o[half][dt][3] * inv);
      *reinterpret_cast<ushort4_*>(
          &ctx[((size_t)b * 2048 + s) * 2048 + h * 128 + d0]) = pk;
    }
  }
}

extern "C" void kernel_launch(void* const* d_in, const int* in_sizes, int n_in,
                              void* d_out, int out_size, void* d_ws, size_t ws_size,
                              hipStream_t stream) {
  const float* x = (const float*)d_in[0];
  const float* w_qkv = (const float*)d_in[1];
  const float* b_qkv = (const float*)d_in[2];
  const float* w_o = (const float*)d_in[3];
  float* outp = (float*)d_out;

  unsigned short* ws = (unsigned short*)d_ws;
  unsigned short* xb    = ws;
  unsigned short* wqkvT = xb + 8388608;
  unsigned short* woT   = wqkvT + 12582912;
  unsigned short* qbuf  = woT + 4194304;
  unsigned short* kbuf  = qbuf + 8388608;
  unsigned short* vtbuf = kbuf + 8388608;
  unsigned short* ctxb  = vtbuf + 8388608;

  k_prep<<<12288, 256, 0, stream>>>(x, xb, w_qkv, wqkvT, w_o, woT);
  // QKV split into per-segment launches (diagnostic + identical total work)
  k_gemm<0><<<dim3(16, 32), 256, 0, stream>>>(xb, wqkvT, b_qkv, qbuf, nullptr);
  k_gemm<1><<<dim3(16, 32), 256, 0, stream>>>(xb, wqkvT + (size_t)4194304, b_qkv + 2048, kbuf, nullptr);
  k_gemm<2><<<dim3(16, 32), 256, 0, stream>>>(xb, wqkvT + (size_t)8388608, b_qkv + 4096, vtbuf, nullptr);
  k_attn<<<dim3(16, 32), 256, 0, stream>>>(qbuf, kbuf, vtbuf, ctxb);
  k_gemm<3><<<dim3(16, 32), 256, 0, stream>>>(ctxb, woT, nullptr, nullptr, outp);
}

// Round 4
// 399.400 us; speedup vs baseline: 1.0466x; 1.0162x over previous
//
#include <hip/hip_runtime.h>
#include <cstdint>
#include <cstddef>

typedef __attribute__((ext_vector_type(8))) short bf16x8;
typedef __attribute__((ext_vector_type(4))) float f32x4;
typedef __attribute__((ext_vector_type(4))) unsigned short ushort4_;

#define MFMA16(a, b, c) __builtin_amdgcn_mfma_f32_16x16x32_bf16((a), (b), (c), 0, 0, 0)

__device__ __forceinline__ unsigned short f2bf(float f) {
  union { float f; unsigned u; } c; c.f = f;
  unsigned r = c.u + 0x7fffu + ((c.u >> 16) & 1u);
  return (unsigned short)(r >> 16);
}

// async global->LDS, 16B per lane. LDS ptr must be wave-uniform; HW writes
// lane i at lds + i*16 (m97/m104). Swizzle goes into the SOURCE address.
__device__ __forceinline__ void gl_lds16(const unsigned short* g, unsigned short* l) {
  __builtin_amdgcn_global_load_lds(
      (const __attribute__((address_space(1))) void*)g,
      (__attribute__((address_space(3))) void*)l, 16, 0, 0);
}

// ---------------- fused prep: x->bf16 cvt + both weight transposes ----------------
// blocks [0,8192): cvt; [8192,11264): w_qkv^T (96x32); [11264,12288): w_o^T (32x32)
__global__ __launch_bounds__(256) void k_prep(const float* __restrict__ x,
                                              unsigned short* __restrict__ xb,
                                              const float* __restrict__ wqkv,
                                              unsigned short* __restrict__ wqkvT,
                                              const float* __restrict__ wo,
                                              unsigned short* __restrict__ woT) {
  __shared__ unsigned short t[64][65];
  const int blk = blockIdx.x;
  const int tid = threadIdx.x;
  if (blk < 8192) {
    int i = blk * 256 + tid;
    float4 v = reinterpret_cast<const float4*>(x)[i];
    ushort4_ o;
    o.x = f2bf(v.x); o.y = f2bf(v.y); o.z = f2bf(v.z); o.w = f2bf(v.w);
    reinterpret_cast<ushort4_*>(xb)[i] = o;
    return;
  }
  const float* W;
  unsigned short* WT;
  int n0, k0, N;
  if (blk < 11264) {
    int local = blk - 8192;
    W = wqkv; WT = wqkvT; N = 6144;
    n0 = (local % 96) * 64; k0 = (local / 96) * 64;
  } else {
    int local = blk - 11264;
    W = wo; WT = woT; N = 2048;
    n0 = (local % 32) * 64; k0 = (local / 32) * 64;
  }
#pragma unroll
  for (int i = 0; i < 16; i++) {
    int li = tid + i * 256;
    int kk = li >> 6, nn = li & 63;
    t[kk][nn] = f2bf(W[(size_t)(k0 + kk) * N + (n0 + nn)]);
  }
  __syncthreads();
#pragma unroll
  for (int i = 0; i < 16; i++) {
    int li = tid + i * 256;
    int nn = li >> 6, kk = li & 63;
    WT[(size_t)(n0 + nn) * 2048 + (k0 + kk)] = t[kk][nn];
  }
}

// ---------------- GEMM: C[128x128]/block, A[M][2048] bf16, Bt[N][2048] bf16
// MODE 0: monolithic QKV (N=6144). Q rows are PRE-SCALED by sl2 = rsqrt(128)
// *log2(e) in the fp32 epilogue so attention's softmax needs no per-element
// scale mul. MODE 1: out-projection, fp32 output.
template <int MODE>
__global__ __launch_bounds__(256) void k_gemm(const unsigned short* __restrict__ A,
                                              const unsigned short* __restrict__ Bt,
                                              const float* __restrict__ bias,
                                              unsigned short* __restrict__ qb,
                                              unsigned short* __restrict__ kb,
                                              unsigned short* __restrict__ vtb,
                                              float* __restrict__ outp) {
  __shared__ __align__(16) unsigned short As[128 * 64];
  __shared__ __align__(16) unsigned short Bs[128 * 64];
  const int tid = threadIdx.x;
  const int lane = tid & 63, wid = tid >> 6;
  const int quad = lane >> 4, l16 = lane & 15;
  const int wm = wid >> 1, wn = wid & 1;
  const int m0 = blockIdx.y * 128, n0 = blockIdx.x * 128;

  f32x4 acc[4][4];
#pragma unroll
  for (int i = 0; i < 4; i++)
#pragma unroll
    for (int j = 0; j < 4; j++) {
      f32x4 z = {0.f, 0.f, 0.f, 0.f};
      acc[i][j] = z;
    }

  for (int k0 = 0; k0 < 2048; k0 += 64) {
    __syncthreads();
#pragma unroll
    for (int i = 0; i < 4; i++) {
      int slotbase = wid * 64 + i * 256;
      int slot = slotbase + lane;
      int row = slot >> 3, chs = slot & 7, gch = chs ^ (row & 7);
      gl_lds16(A + (size_t)(m0 + row) * 2048 + k0 + gch * 8, &As[slotbase * 8]);
      gl_lds16(Bt + (size_t)(n0 + row) * 2048 + k0 + gch * 8, &Bs[slotbase * 8]);
    }
    __syncthreads();
#pragma unroll
    for (int kc = 0; kc < 2; kc++) {
      bf16x8 af[4], bfr[4];
#pragma unroll
      for (int mt = 0; mt < 4; mt++) {
        int r = wm * 64 + mt * 16 + l16;
        int ch = kc * 4 + quad;
        af[mt] = *reinterpret_cast<const bf16x8*>(&As[r * 64 + ((ch ^ (r & 7)) * 8)]);
      }
#pragma unroll
      for (int nt = 0; nt < 4; nt++) {
        int r = wn * 64 + nt * 16 + l16;
        int ch = kc * 4 + quad;
        bfr[nt] = *reinterpret_cast<const bf16x8*>(&Bs[r * 64 + ((ch ^ (r & 7)) * 8)]);
      }
#pragma unroll
      for (int mt = 0; mt < 4; mt++)
#pragma unroll
        for (int nt = 0; nt < 4; nt++)
          acc[mt][nt] = MFMA16(af[mt], bfr[nt], acc[mt][nt]);
    }
  }

  const int mbase = m0 + wm * 64;
  const int nbase = n0 + wn * 64;
  if (MODE == 0) {
#pragma unroll
    for (int nt = 0; nt < 4; nt++) {
      int n = nbase + nt * 16 + l16;
      float bv = bias[n];
      int seg = n >> 11;  // 0=q,1=k,2=v
      int h = (n >> 7) & 15;
      int d = n & 127;
      float sc = (seg == 0) ? 0.12751741f : 1.0f;  // Q pre-scale (sl2)
#pragma unroll
      for (int mt = 0; mt < 4; mt++) {
        int mrow = mbase + mt * 16 + quad * 4;
        int b = mrow >> 11, s = mrow & 2047;
        if (seg == 2) {
          ushort4_ pk;
          pk.x = f2bf(acc[mt][nt][0] + bv);
          pk.y = f2bf(acc[mt][nt][1] + bv);
          pk.z = f2bf(acc[mt][nt][2] + bv);
          pk.w = f2bf(acc[mt][nt][3] + bv);
          *reinterpret_cast<ushort4_*>(vtb + ((size_t)(b * 16 + h) * 128 + d) * 2048 + s) = pk;
        } else {
          unsigned short* dst = (seg == 0 ? qb : kb);
          size_t base = (size_t)(b * 16 + h) * 2048;
#pragma unroll
          for (int rg = 0; rg < 4; rg++)
            dst[(base + (s + rg)) * 128 + d] = f2bf((acc[mt][nt][rg] + bv) * sc);
        }
      }
    }
  } else {
#pragma unroll
    for (int nt = 0; nt < 4; nt++) {
      int n = nbase + nt * 16 + l16;
#pragma unroll
      for (int mt = 0; mt < 4; mt++) {
        int mrow = mbase + mt * 16 + quad * 4;
#pragma unroll
        for (int rg = 0; rg < 4; rg++)
          outp[(size_t)(mrow + rg) * 2048 + n] = acc[mt][nt][rg];
      }
    }
  }
}

// ---------------- flash attention: folded causal pairs, uniform duration ----------------
// q-tiles of 64 rows (32 tiles). Block j owns tile j (half0) + tile 31-j
// (half1); wave w gets rows base+w*16 of each. Every block runs nkv=32-j
// KV-tiles; half0 compute gated off (uniform branch) once kv>j. Per-wave
// compute = (j+1)+(32-j) = 33 half-tile units for ALL blocks -> all 512
// blocks finish together, both CU slots stay full (fixes 13% occupancy:
// the R1 pairing balanced per-CU totals but left solo-block phases).
// S^T = K·Q^T, per-lane online softmax (Q pre-scaled by sl2 in k_gemm),
// defer-max rescale (T13), O^T accumulation. LDS 80KB -> 2 blocks/CU.
__global__ __launch_bounds__(256, 2) void k_attn(const unsigned short* __restrict__ qb,
                                                 const unsigned short* __restrict__ kb,
                                                 const unsigned short* __restrict__ vtb,
                                                 unsigned short* __restrict__ ctx) {
  __shared__ __align__(16) unsigned short Ks[2][64 * 128];  // [buf][key][dim]
  __shared__ __align__(16) unsigned short Vs[2][128 * 64];  // [buf][dim][key]
  __shared__ __align__(16) unsigned short Ps[128 * 64];     // [q][key]
  const int j = blockIdx.x;   // 0..15
  const int bh = blockIdx.y;
  const int tid = threadIdx.x;
  const int lane = tid & 63, w = tid >> 6;
  const int quad = lane >> 4, l16 = lane & 15;
  const unsigned short* Qh = qb + (size_t)bh * 2048 * 128;
  const unsigned short* Kh = kb + (size_t)bh * 2048 * 128;
  const unsigned short* Vh = vtb + (size_t)bh * 128 * 2048;

  const int base0 = j * 64 + w * 16;         // half0 rows (low tile)
  const int base1 = (31 - j) * 64 + w * 16;  // half1 rows (high tile)
  const int nkv = 32 - j;

  // Q fragments (B-operand: n=q at l16, k=d at kc*32+quad*8)
  bf16x8 qf[2][4];
#pragma unroll
  for (int kc = 0; kc < 4; kc++) {
    qf[0][kc] = *reinterpret_cast<const bf16x8*>(
        Qh + (size_t)(base0 + l16) * 128 + kc * 32 + quad * 8);
    qf[1][kc] = *reinterpret_cast<const bf16x8*>(
        Qh + (size_t)(base1 + l16) * 128 + kc * 32 + quad * 8);
  }

  f32x4 o[2][8];
#pragma unroll
  for (int half = 0; half < 2; half++)
#pragma unroll
    for (int dt = 0; dt < 8; dt++) {
      f32x4 z = {0.f, 0.f, 0.f, 0.f};
      o[half][dt] = z;
    }
  float m_run[2] = {-1e30f, -1e30f}, l_run[2] = {0.f, 0.f};

  auto stage = [&](int kvb, int bsel) {
    unsigned short* Kd = &Ks[bsel][0];
    unsigned short* Vd = &Vs[bsel][0];
#pragma unroll
    for (int i = 0; i < 4; i++) {
      int slotbase = i * 256 + w * 64;
      int slot = slotbase + lane;
      int rowk = slot >> 4, chk = (slot & 15) ^ (rowk & 7);
      gl_lds16(Kh + (size_t)(kvb + rowk) * 128 + chk * 8, Kd + slotbase * 8);
      int rowv = slot >> 3, chv = (slot & 7) ^ (rowv & 7);
      gl_lds16(Vh + (size_t)rowv * 2048 + kvb + chv * 8, Vd + slotbase * 8);
    }
  };

  // softmax for one half; compile-time-resolved refs (no runtime array idx)
  auto softmax_half = [&](f32x4 (&sa)[4], f32x4 (&oo)[8], float& mr, float& lr,
                          int qb_h, int psrow, int kvb) {
    const bool needmask = (kvb + 63) > qb_h;
    const int qabs = qb_h + l16;
    float tmax = -1e30f;
#pragma unroll
    for (int nt = 0; nt < 4; nt++)
#pragma unroll
      for (int rg = 0; rg < 4; rg++) {
        float v = sa[nt][rg];
        if (needmask && (kvb + nt * 16 + quad * 4 + rg) > qabs) v = -1e30f;
        sa[nt][rg] = v;
        tmax = fmaxf(tmax, v);
      }
    tmax = fmaxf(tmax, __shfl_xor(tmax, 16));
    tmax = fmaxf(tmax, __shfl_xor(tmax, 32));
    // defer-max (T13): rescale only when the tile max grew by > 8 log2 units;
    // deferred P bounded by 2^8, f32 accum headroom fine.
    if (!__all(tmax - mr <= 8.f)) {
      float mnew = fmaxf(mr, tmax);
      float alpha = exp2f(mr - mnew);
      mr = mnew;
      lr *= alpha;
#pragma unroll
      for (int dt = 0; dt < 8; dt++)
#pragma unroll
        for (int rg = 0; rg < 4; rg++) oo[dt][rg] *= alpha;
    }
    const float mcur = mr;
    float rsum = 0.f;
#pragma unroll
    for (int nt = 0; nt < 4; nt++)
#pragma unroll
      for (int rg = 0; rg < 4; rg++) {
        float p = exp2f(sa[nt][rg] - mcur);
        sa[nt][rg] = p;
        rsum += p;
      }
    rsum += __shfl_xor(rsum, 16);
    rsum += __shfl_xor(rsum, 32);
    lr += rsum;
    // P^T -> Ps[q][key], 8B stores, 16B-chunk swizzle
#pragma unroll
    for (int nt = 0; nt < 4; nt++) {
      ushort4_ pk;
      pk.x = f2bf(sa[nt][0]);
      pk.y = f2bf(sa[nt][1]);
      pk.z = f2bf(sa[nt][2]);
      pk.w = f2bf(sa[nt][3]);
      int chunk = nt * 2 + (quad >> 1);
      *reinterpret_cast<ushort4_*>(
          &Ps[(psrow + l16) * 64 + ((chunk ^ (l16 & 7)) * 8) + (quad & 1) * 4]) = pk;
    }
  };

  stage(0, 0);

  for (int kv = 0; kv < nkv; kv++) {
    const int kvb = kv * 64;
    const int cur = kv & 1;
    asm volatile("s_waitcnt vmcnt(0)" ::: "memory");
    asm volatile("s_barrier" ::: "memory");
    if (kv + 1 < nkv) stage(kvb + 64, cur ^ 1);
    const bool dual = (kv <= j);  // uniform per block

    const unsigned short* Kc = &Ks[cur][0];
    const unsigned short* Vc = &Vs[cur][0];

    f32x4 sacc[2][4];
#pragma unroll
    for (int half = 0; half < 2; half++)
#pragma unroll
      for (int nt = 0; nt < 4; nt++) {
        f32x4 z = {0.f, 0.f, 0.f, 0.f};
        sacc[half][nt] = z;
      }
    if (dual) {
#pragma unroll
      for (int kc = 0; kc < 4; kc++)
#pragma unroll
        for (int nt = 0; nt < 4; nt++) {
          int r = nt * 16 + l16, ch = kc * 4 + quad;
          bf16x8 kf = *reinterpret_cast<const bf16x8*>(&Kc[r * 128 + ((ch ^ (r & 7)) * 8)]);
          sacc[0][nt] = MFMA16(kf, qf[0][kc], sacc[0][nt]);
          sacc[1][nt] = MFMA16(kf, qf[1][kc], sacc[1][nt]);
        }
    } else {
#pragma unroll
      for (int kc = 0; kc < 4; kc++)
#pragma unroll
        for (int nt = 0; nt < 4; nt++) {
          int r = nt * 16 + l16, ch = kc * 4 + quad;
          bf16x8 kf = *reinterpret_cast<const bf16x8*>(&Kc[r * 128 + ((ch ^ (r & 7)) * 8)]);
          sacc[1][nt] = MFMA16(kf, qf[1][kc], sacc[1][nt]);
        }
    }

    softmax_half(sacc[1], o[1], m_run[1], l_run[1], base1, w * 32 + 16, kvb);
    if (dual) softmax_half(sacc[0], o[0], m_run[0], l_run[0], base0, w * 32, kvb);
    asm volatile("s_waitcnt lgkmcnt(0)" ::: "memory");  // same-wave rows only

    if (dual) {
#pragma unroll
      for (int kc = 0; kc < 2; kc++) {
        int chunkr = kc * 4 + quad;
        bf16x8 pf0 = *reinterpret_cast<const bf16x8*>(
            &Ps[(w * 32 + l16) * 64 + ((chunkr ^ (l16 & 7)) * 8)]);
        bf16x8 pf1 = *reinterpret_cast<const bf16x8*>(
            &Ps[(w * 32 + 16 + l16) * 64 + ((chunkr ^ (l16 & 7)) * 8)]);
#pragma unroll
        for (int dt = 0; dt < 8; dt++) {
          int r = dt * 16 + l16, ch = kc * 4 + quad;
          bf16x8 vf = *reinterpret_cast<const bf16x8*>(&Vc[r * 64 + ((ch ^ (r & 7)) * 8)]);
          o[0][dt] = MFMA16(vf, pf0, o[0][dt]);
          o[1][dt] = MFMA16(vf, pf1, o[1][dt]);
        }
      }
    } else {
#pragma unroll
      for (int kc = 0; kc < 2; kc++) {
        int chunkr = kc * 4 + quad;
        bf16x8 pf1 = *reinterpret_cast<const bf16x8*>(
            &Ps[(w * 32 + 16 + l16) * 64 + ((chunkr ^ (l16 & 7)) * 8)]);
#pragma unroll
        for (int dt = 0; dt < 8; dt++) {
          int r = dt * 16 + l16, ch = kc * 4 + quad;
          bf16x8 vf = *reinterpret_cast<const bf16x8*>(&Vc[r * 64 + ((ch ^ (r & 7)) * 8)]);
          o[1][dt] = MFMA16(vf, pf1, o[1][dt]);
        }
      }
    }
  }

  const int b = bh >> 4, h = bh & 15;
#pragma unroll
  for (int half = 0; half < 2; half++) {
    const float inv = 1.f / l_run[half];
    const int s = (half == 0 ? base0 : base1) + l16;
#pragma unroll
    for (int dt = 0; dt < 8; dt++) {
      int d0 = dt * 16 + quad * 4;
      ushort4_ pk;
      pk.x = f2bf(o[half][dt][0] * inv);
      pk.y = f2bf(o[half][dt][1] * inv);
      pk.z = f2bf(o[half][dt][2] * inv);
      pk.w = f2bf(o[half][dt][3] * inv);
      *reinterpret_cast<ushort4_*>(
          &ctx[((size_t)b * 2048 + s) * 2048 + h * 128 + d0]) = pk;
    }
  }
}

extern "C" void kernel_launch(void* const* d_in, const int* in_sizes, int n_in,
                              void* d_out, int out_size, void* d_ws, size_t ws_size,
                              hipStream_t stream) {
  const float* x = (const float*)d_in[0];
  const float* w_qkv = (const float*)d_in[1];
  const float* b_qkv = (const float*)d_in[2];
  const float* w_o = (const float*)d_in[3];
  float* outp = (float*)d_out;

  unsigned short* ws = (unsigned short*)d_ws;
  unsigned short* xb    = ws;
  unsigned short* wqkvT = xb + 8388608;
  unsigned short* woT   = wqkvT + 12582912;
  unsigned short* qbuf  = woT + 4194304;
  unsigned short* kbuf  = qbuf + 8388608;
  unsigned short* vtbuf = kbuf + 8388608;
  unsigned short* ctxb  = vtbuf + 8388608;

  k_prep<<<12288, 256, 0, stream>>>(x, xb, w_qkv, wqkvT, w_o, woT);
  k_gemm<0><<<dim3(48, 32), 256, 0, stream>>>(xb, wqkvT, b_qkv, qbuf, kbuf, vtbuf, nullptr);
  k_attn<<<dim3(16, 32), 256, 0, stream>>>(qbuf, kbuf, vtbuf, ctxb);
  k_gemm<1><<<dim3(16, 32), 256, 0, stream>>>(ctxb, woT, nullptr, nullptr, nullptr, nullptr, outp);
}